// Round 1
// baseline (2250.198 us; speedup 1.0000x reference)
//
#include <hip/hip_runtime.h>

#define BATCH 2
#define SEQ   2048
#define CH    1024
#define NH    16
#define HD    64
#define BHN   (BATCH*NH)   /* 32 */
#define SD    (SEQ*HD)     /* 131072 */
#define QT    32
#define KT    32
#define BAND  (QT+KT-1)    /* 63 */

// ---------------------------------------------------------------------------
// Projection GEMM: out[m][n] = sum_k X[m][k]*W[n][k] + bias[n]
// M=4096 (B*S), N=K=1024. Tile 128x128, K-step 16, 256 threads, 8x8/thread.
// blockIdx.z selects q/k/v.
// ---------------------------------------------------------------------------
__global__ __launch_bounds__(256) void proj_gemm_kernel(
    const float* __restrict__ X,
    const float* __restrict__ Wq, const float* __restrict__ bq,
    const float* __restrict__ Wk, const float* __restrict__ bk,
    const float* __restrict__ Wv, const float* __restrict__ bv,
    float* __restrict__ qo, float* __restrict__ ko, float* __restrict__ vo)
{
    const int z = blockIdx.z;
    const float* W    = (z == 0) ? Wq : (z == 1) ? Wk : Wv;
    const float* bias = (z == 0) ? bq : (z == 1) ? bk : bv;
    float*       out  = (z == 0) ? qo : (z == 1) ? ko : vo;

    const int m0 = blockIdx.y * 128;
    const int n0 = blockIdx.x * 128;
    const int tid = threadIdx.x;
    const int tx = tid & 15, ty = tid >> 4;

    __shared__ float a_lds[16][132];   // [kk][m]
    __shared__ float b_lds[16][132];   // [kk][n]

    float acc[8][8];
#pragma unroll
    for (int i = 0; i < 8; i++)
#pragma unroll
        for (int j = 0; j < 8; j++) acc[i][j] = 0.f;

    for (int k0 = 0; k0 < 1024; k0 += 16) {
        __syncthreads();
#pragma unroll
        for (int l = 0; l < 2; l++) {
            int f  = tid + l * 256;
            int r  = f >> 2;        // 0..127
            int c4 = (f & 3) * 4;   // k offset within tile
            float4 a = *(const float4*)(X + (size_t)(m0 + r) * 1024 + k0 + c4);
            a_lds[c4 + 0][r] = a.x; a_lds[c4 + 1][r] = a.y;
            a_lds[c4 + 2][r] = a.z; a_lds[c4 + 3][r] = a.w;
            float4 b = *(const float4*)(W + (size_t)(n0 + r) * 1024 + k0 + c4);
            b_lds[c4 + 0][r] = b.x; b_lds[c4 + 1][r] = b.y;
            b_lds[c4 + 2][r] = b.z; b_lds[c4 + 3][r] = b.w;
        }
        __syncthreads();
#pragma unroll
        for (int kk = 0; kk < 16; kk++) {
            float4 a0 = *(const float4*)&a_lds[kk][ty * 8];
            float4 a1 = *(const float4*)&a_lds[kk][ty * 8 + 4];
            float4 b0 = *(const float4*)&b_lds[kk][tx * 8];
            float4 b1 = *(const float4*)&b_lds[kk][tx * 8 + 4];
            float av[8] = {a0.x, a0.y, a0.z, a0.w, a1.x, a1.y, a1.z, a1.w};
            float bw[8] = {b0.x, b0.y, b0.z, b0.w, b1.x, b1.y, b1.z, b1.w};
#pragma unroll
            for (int i = 0; i < 8; i++)
#pragma unroll
                for (int j = 0; j < 8; j++)
                    acc[i][j] += av[i] * bw[j];
        }
    }

#pragma unroll
    for (int i = 0; i < 8; i++) {
        const int m = m0 + ty * 8 + i;
        const int n = n0 + tx * 8;
        float4 o0, o1;
        o0.x = acc[i][0] + bias[n + 0]; o0.y = acc[i][1] + bias[n + 1];
        o0.z = acc[i][2] + bias[n + 2]; o0.w = acc[i][3] + bias[n + 3];
        o1.x = acc[i][4] + bias[n + 4]; o1.y = acc[i][5] + bias[n + 5];
        o1.z = acc[i][6] + bias[n + 6]; o1.w = acc[i][7] + bias[n + 7];
        *(float4*)(out + (size_t)m * 1024 + n)     = o0;
        *(float4*)(out + (size_t)m * 1024 + n + 4) = o1;
    }
}

// ---------------------------------------------------------------------------
// Flash attention with relative-position scores.
// scores[b,h,s,t] = ( dot(Q2[b,h,s,:], K2[b,h,t,:])
//                   + dot(q_r[s,bh,:], relk[t-s+2047,:]) ) / 8
// Q2[b,h,s,d]  = qbuf[bh*131072 + s*64 + d]          (raw view #1)
// q_r[s,bh,d]  = qbuf[s*2048 + bh*64 + d]            (raw view #2)
// out[b, s0+i, h*64+d] = softmax_t(scores) @ V2
// One block per (s-tile of 32, bh). 256 threads = 16tx x 16ty.
// Thread owns score tile rows {ty*2, ty*2+1} x cols {tx*2, tx*2+1},
// O-accum rows x d-cols {tx*4..+3}.
// ---------------------------------------------------------------------------
__global__ __launch_bounds__(256) void attn_kernel(
    const float* __restrict__ qbuf, const float* __restrict__ kbuf,
    const float* __restrict__ vbuf, const float* __restrict__ relk,
    float* __restrict__ out)
{
    const int tid = threadIdx.x;
    const int tx = tid & 15, ty = tid >> 4;
    const int bh = blockIdx.y;            // 0..31
    const int b  = bh >> 4, h = bh & 15;
    const int s0 = blockIdx.x * QT;

    __shared__ float qc[QT][HD + 1];      // content q rows
    __shared__ float qr[QT][HD + 1];      // rel-pos q rows (view #2)
    __shared__ float kt_s[KT][HD + 1];
    __shared__ float vt_s[KT][HD + 4];    // stride 68: float4-aligned rows
    __shared__ float pt_s[QT][KT + 4];
    __shared__ float band[BAND][HD + 1];  // rel table diagonal band

    const size_t bh_off = (size_t)bh * SD;

    // Load qc (contiguous 32*64 chunk) and qr rows (stride 2048).
    for (int f = tid; f < QT * HD / 4; f += 256) {
        int r = f >> 4;
        int c = (f & 15) * 4;
        float4 v = *(const float4*)(qbuf + bh_off + (size_t)s0 * HD + r * HD + c);
        qc[r][c] = v.x; qc[r][c + 1] = v.y; qc[r][c + 2] = v.z; qc[r][c + 3] = v.w;
        float4 u = *(const float4*)(qbuf + (size_t)(s0 + r) * (BHN * HD) + (size_t)bh * HD + c);
        qr[r][c] = u.x; qr[r][c + 1] = u.y; qr[r][c + 2] = u.z; qr[r][c + 3] = u.w;
    }

    float m_i[2] = {-1e30f, -1e30f};
    float l_i[2] = {0.f, 0.f};
    float o_acc[2][4] = {{0.f, 0.f, 0.f, 0.f}, {0.f, 0.f, 0.f, 0.f}};

    const int r0 = ty * 2, r1 = ty * 2 + 1;
    const int j0 = tx * 2, j1 = tx * 2 + 1;

    for (int t0 = 0; t0 < SEQ; t0 += KT) {
        __syncthreads();   // previous iteration's LDS consumers done
        // K/V tiles: contiguous 32*64-float chunks
        for (int f = tid; f < KT * HD / 4; f += 256) {
            int r = f >> 4;
            int c = (f & 15) * 4;
            float4 kv = *(const float4*)(kbuf + bh_off + (size_t)t0 * HD + r * HD + c);
            kt_s[r][c] = kv.x; kt_s[r][c + 1] = kv.y;
            kt_s[r][c + 2] = kv.z; kt_s[r][c + 3] = kv.w;
            float4 vv = *(const float4*)(vbuf + bh_off + (size_t)t0 * HD + r * HD + c);
            *(float4*)&vt_s[r][c] = vv;
        }
        // rel band: rows u_lo..u_lo+62, u_lo = t0-s0+2047-31; x = j-i+31
        const int u_lo = t0 - s0 + (SEQ - 1) - (QT - 1);
        for (int f = tid; f < BAND * HD / 4; f += 256) {
            int r = f >> 4;
            int c = (f & 15) * 4;
            float4 rv = *(const float4*)(relk + (size_t)(u_lo + r) * HD + c);
            band[r][c] = rv.x; band[r][c + 1] = rv.y;
            band[r][c + 2] = rv.z; band[r][c + 3] = rv.w;
        }
        __syncthreads();

        // 2x2 score tile. Band rows: (r0,j0)->x0, (r0,j1)->x0+1,
        // (r1,j0)->x0-1, (r1,j1)->x0  (only 3 distinct reads per d).
        float s00 = 0.f, s01 = 0.f, s10 = 0.f, s11 = 0.f;
        const int x0 = j0 - r0 + (QT - 1);   // in [1, 61]
#pragma unroll 8
        for (int d = 0; d < HD; d++) {
            float a0 = qc[r0][d], a1 = qc[r1][d];
            float k0v = kt_s[j0][d], k1v = kt_s[j1][d];
            float q0 = qr[r0][d], q1 = qr[r1][d];
            float e0 = band[x0][d];
            float ep = band[x0 + 1][d];
            float em = band[x0 - 1][d];
            s00 += a0 * k0v + q0 * e0;
            s01 += a0 * k1v + q0 * ep;
            s10 += a1 * k0v + q1 * em;
            s11 += a1 * k1v + q1 * e0;
        }
        const float scale = 0.125f;   // 1/sqrt(64)
        s00 *= scale; s01 *= scale; s10 *= scale; s11 *= scale;

        // Online softmax, rows reduced across the 16 tx lanes (same ty group).
        float mx0 = fmaxf(s00, s01);
        float mx1 = fmaxf(s10, s11);
#pragma unroll
        for (int off = 1; off < 16; off <<= 1) {
            mx0 = fmaxf(mx0, __shfl_xor(mx0, off));
            mx1 = fmaxf(mx1, __shfl_xor(mx1, off));
        }
        float mn0 = fmaxf(m_i[0], mx0);
        float mn1 = fmaxf(m_i[1], mx1);
        float al0 = __expf(m_i[0] - mn0);
        float al1 = __expf(m_i[1] - mn1);
        float p00 = __expf(s00 - mn0), p01 = __expf(s01 - mn0);
        float p10 = __expf(s10 - mn1), p11 = __expf(s11 - mn1);
        float rs0 = p00 + p01, rs1 = p10 + p11;
#pragma unroll
        for (int off = 1; off < 16; off <<= 1) {
            rs0 += __shfl_xor(rs0, off);
            rs1 += __shfl_xor(rs1, off);
        }
        l_i[0] = l_i[0] * al0 + rs0;  m_i[0] = mn0;
        l_i[1] = l_i[1] * al1 + rs1;  m_i[1] = mn1;
#pragma unroll
        for (int c = 0; c < 4; c++) { o_acc[0][c] *= al0; o_acc[1][c] *= al1; }
        pt_s[r0][j0] = p00; pt_s[r0][j1] = p01;
        pt_s[r1][j0] = p10; pt_s[r1][j1] = p11;
        __syncthreads();

        // PV: o[i][d] += sum_j P[i][j] * V[j][d], d = tx*4..+3
#pragma unroll 8
        for (int j = 0; j < KT; j++) {
            float4 vv = *(const float4*)&vt_s[j][tx * 4];
            float p0 = pt_s[r0][j], p1 = pt_s[r1][j];
            o_acc[0][0] += p0 * vv.x; o_acc[0][1] += p0 * vv.y;
            o_acc[0][2] += p0 * vv.z; o_acc[0][3] += p0 * vv.w;
            o_acc[1][0] += p1 * vv.x; o_acc[1][1] += p1 * vv.y;
            o_acc[1][2] += p1 * vv.z; o_acc[1][3] += p1 * vv.w;
        }
    }

    const float inv0 = 1.f / l_i[0];
    const float inv1 = 1.f / l_i[1];
    const size_t base0 = ((size_t)b * SEQ + s0 + r0) * CH + h * HD + tx * 4;
    const size_t base1 = ((size_t)b * SEQ + s0 + r1) * CH + h * HD + tx * 4;
    float4 o0, o1;
    o0.x = o_acc[0][0] * inv0; o0.y = o_acc[0][1] * inv0;
    o0.z = o_acc[0][2] * inv0; o0.w = o_acc[0][3] * inv0;
    o1.x = o_acc[1][0] * inv1; o1.y = o_acc[1][1] * inv1;
    o1.z = o_acc[1][2] * inv1; o1.w = o_acc[1][3] * inv1;
    *(float4*)(out + base0) = o0;
    *(float4*)(out + base1) = o1;
}

// ---------------------------------------------------------------------------
extern "C" void kernel_launch(void* const* d_in, const int* in_sizes, int n_in,
                              void* d_out, int out_size, void* d_ws, size_t ws_size,
                              hipStream_t stream)
{
    const float* src  = (const float*)d_in[0];
    const float* Wq   = (const float*)d_in[1];
    const float* bq   = (const float*)d_in[2];
    const float* Wk   = (const float*)d_in[3];
    const float* bk   = (const float*)d_in[4];
    const float* Wv   = (const float*)d_in[5];
    const float* bv   = (const float*)d_in[6];
    const float* relk = (const float*)d_in[7];
    float* out = (float*)d_out;

    float* qbuf = (float*)d_ws;                       // 4096*1024 floats
    float* kbuf = qbuf + (size_t)BATCH * SEQ * CH;
    float* vbuf = kbuf + (size_t)BATCH * SEQ * CH;    // total 48 MiB of ws

    dim3 gProj(1024 / 128, 4096 / 128, 3);            // (8, 32, 3)
    proj_gemm_kernel<<<gProj, 256, 0, stream>>>(src, Wq, bq, Wk, bk, Wv, bv,
                                                qbuf, kbuf, vbuf);

    dim3 gAttn(SEQ / QT, BHN);                        // (64, 32)
    attn_kernel<<<gAttn, 256, 0, stream>>>(qbuf, kbuf, vbuf, relk, out);
}

// Round 2
// 683.265 us; speedup vs baseline: 3.2933x; 3.2933x over previous
//
#include <hip/hip_runtime.h>

#define BATCH 2
#define SEQ   2048
#define CH    1024
#define NH    16
#define HD    64
#define BHN   (BATCH*NH)   /* 32 */
#define SD    (SEQ*HD)     /* 131072 */

typedef short v8s __attribute__((ext_vector_type(8)));
typedef short v4s __attribute__((ext_vector_type(4)));
typedef float v4f __attribute__((ext_vector_type(4)));

__device__ __forceinline__ short f2bf(float f) {
    unsigned u = __float_as_uint(f);
    u += 0x7fff + ((u >> 16) & 1);   // RNE; inputs here are finite
    return (short)(u >> 16);
}

// ---------------------------------------------------------------------------
// rel_k_table fp32 -> bf16
// ---------------------------------------------------------------------------
__global__ __launch_bounds__(256) void cast_rel_kernel(
    const float* __restrict__ r, short* __restrict__ o, int n4)
{
    int i = blockIdx.x * 256 + threadIdx.x;
    if (i < n4) {
        float4 v = ((const float4*)r)[i];
        v4s s; s.x = f2bf(v.x); s.y = f2bf(v.y); s.z = f2bf(v.z); s.w = f2bf(v.w);
        ((v4s*)o)[i] = s;
    }
}

// ---------------------------------------------------------------------------
// Projection GEMM (fp32 vector compute, bf16 output).
// out[m][n] = sum_k X[m][k]*W[n][k] + bias[n];  M=4096, N=K=1024.
// ---------------------------------------------------------------------------
__global__ __launch_bounds__(256) void proj_gemm_kernel(
    const float* __restrict__ X,
    const float* __restrict__ Wq, const float* __restrict__ bq,
    const float* __restrict__ Wk, const float* __restrict__ bk,
    const float* __restrict__ Wv, const float* __restrict__ bv,
    short* __restrict__ qo, short* __restrict__ ko, short* __restrict__ vo)
{
    const int z = blockIdx.z;
    const float* W    = (z == 0) ? Wq : (z == 1) ? Wk : Wv;
    const float* bias = (z == 0) ? bq : (z == 1) ? bk : bv;
    short*       out  = (z == 0) ? qo : (z == 1) ? ko : vo;

    const int m0 = blockIdx.y * 128;
    const int n0 = blockIdx.x * 128;
    const int tid = threadIdx.x;
    const int tx = tid & 15, ty = tid >> 4;

    __shared__ float a_lds[16][132];
    __shared__ float b_lds[16][132];

    float acc[8][8];
#pragma unroll
    for (int i = 0; i < 8; i++)
#pragma unroll
        for (int j = 0; j < 8; j++) acc[i][j] = 0.f;

    for (int k0 = 0; k0 < 1024; k0 += 16) {
        __syncthreads();
#pragma unroll
        for (int l = 0; l < 2; l++) {
            int f  = tid + l * 256;
            int r  = f >> 2;
            int c4 = (f & 3) * 4;
            float4 a = *(const float4*)(X + (size_t)(m0 + r) * 1024 + k0 + c4);
            a_lds[c4 + 0][r] = a.x; a_lds[c4 + 1][r] = a.y;
            a_lds[c4 + 2][r] = a.z; a_lds[c4 + 3][r] = a.w;
            float4 b = *(const float4*)(W + (size_t)(n0 + r) * 1024 + k0 + c4);
            b_lds[c4 + 0][r] = b.x; b_lds[c4 + 1][r] = b.y;
            b_lds[c4 + 2][r] = b.z; b_lds[c4 + 3][r] = b.w;
        }
        __syncthreads();
#pragma unroll
        for (int kk = 0; kk < 16; kk++) {
            float4 a0 = *(const float4*)&a_lds[kk][ty * 8];
            float4 a1 = *(const float4*)&a_lds[kk][ty * 8 + 4];
            float4 b0 = *(const float4*)&b_lds[kk][tx * 8];
            float4 b1 = *(const float4*)&b_lds[kk][tx * 8 + 4];
            float av[8] = {a0.x, a0.y, a0.z, a0.w, a1.x, a1.y, a1.z, a1.w};
            float bw[8] = {b0.x, b0.y, b0.z, b0.w, b1.x, b1.y, b1.z, b1.w};
#pragma unroll
            for (int i = 0; i < 8; i++)
#pragma unroll
                for (int j = 0; j < 8; j++)
                    acc[i][j] += av[i] * bw[j];
        }
    }

#pragma unroll
    for (int i = 0; i < 8; i++) {
        const int m = m0 + ty * 8 + i;
        const int n = n0 + tx * 8;
        v8s ov;
#pragma unroll
        for (int j = 0; j < 8; j++) ov[j] = f2bf(acc[i][j] + bias[n + j]);
        *(v8s*)(out + (size_t)m * 1024 + n) = ov;
    }
}

// ---------------------------------------------------------------------------
// MFMA flash attention with relative-position scores (all bf16 inputs).
//   score[i][t] = ( q[i]·k[t] + qr[i]·rel[t-i+2047] ) / 8
// Block: 64 q-rows × one bh. 4 waves; wave w owns q-rows i0=w*16..+15.
// K-tile = 32. Rel-pos via skew: R[ii][xl] = qr[i]·band[xw+xl] (GEMM),
// pos[i][j] = R[ii][j-ii+15].
// MFMA 16x16x32 bf16 layouts (HW-verified, learn_hip m89/m120):
//   A[m=lane&15][k=(lane>>4)*8+j], B[n=lane&15][k=(lane>>4)*8+j],
//   C/D: col=lane&15, row=(lane>>4)*4+reg.
// ---------------------------------------------------------------------------
__global__ __launch_bounds__(256, 2) void attn_mfma_kernel(
    const short* __restrict__ qb, const short* __restrict__ kb,
    const short* __restrict__ vb, const short* __restrict__ relb,
    float* __restrict__ out)
{
    const int tid  = threadIdx.x;
    const int w    = tid >> 6;
    const int lane = tid & 63;
    const int l15  = lane & 15;
    const int quad = lane >> 4;
    const int bh = blockIdx.y, b = bh >> 4, h = bh & 15;
    const int s0 = blockIdx.x * 64;
    const int i0 = w * 16;

    __shared__ short qc[64][72];      // content q rows (bf16)
    __shared__ short qr[64][72];      // rel-view q rows
    __shared__ short Kb[32][72];      // key tile
    __shared__ short Vt[64][40];      // V transposed: Vt[d][t]
    __shared__ short band[96][72];    // rel-table diagonal band (95 rows used)
    __shared__ float Rw[4][16][52];   // per-wave skew GEMM result
    __shared__ short Pb[4][16][40];   // per-wave P (bf16) for PV A-operand

    // ---- load q tiles (both views) ----
    for (int f = tid; f < 512; f += 256) {
        int r = f >> 3, c = (f & 7) * 8;
        *(v8s*)&qc[r][c] =
            *(const v8s*)(qb + (size_t)bh * SD + (size_t)(s0 + r) * HD + c);
        *(v8s*)&qr[r][c] =
            *(const v8s*)(qb + (size_t)(s0 + r) * (BHN * HD) + bh * HD + c);
    }

    v4f o_acc[4];
#pragma unroll
    for (int nt = 0; nt < 4; nt++) o_acc[nt] = (v4f)(0.f);
    float m_i[4] = {-1e30f, -1e30f, -1e30f, -1e30f};
    float l_i[4] = {0.f, 0.f, 0.f, 0.f};

    const int xw = 48 - i0;   // wave's band-window start (global band x)

    for (int t0 = 0; t0 < SEQ; t0 += 32) {
        __syncthreads();
        // ---- stage K tile (coalesced) ----
        {
            int t = tid >> 3, c = (tid & 7) * 8;
            *(v8s*)&Kb[t][c] =
                *(const v8s*)(kb + (size_t)bh * SD + (size_t)(t0 + t) * HD + c);
        }
        // ---- stage V tile transposed ----
        {
            int t = tid & 31, c = (tid >> 5) * 8;
            v8s vv = *(const v8s*)(vb + (size_t)bh * SD + (size_t)(t0 + t) * HD + c);
#pragma unroll
            for (int e = 0; e < 8; e++) Vt[c + e][t] = vv[e];
        }
        // ---- stage band: rel rows u_lo..u_lo+94 (row 95 = dup, unread) ----
        const int u_lo = t0 - s0 + (SEQ - 1) - 63;
        for (int f = tid; f < 768; f += 256) {
            int r = f >> 3, c = (f & 7) * 8;
            int rr = (r < 95) ? r : 94;
            *(v8s*)&band[r][c] = *(const v8s*)(relb + (size_t)(u_lo + rr) * HD + c);
        }
        __syncthreads();

        // ---- skew GEMM: R[ii][xl] = sum_d qr[i0+ii][d] * band[xw+xl][d] ----
        {
            v4f racc[3];
#pragma unroll
            for (int nt = 0; nt < 3; nt++) racc[nt] = (v4f)(0.f);
#pragma unroll
            for (int k0 = 0; k0 < 64; k0 += 32) {
                v8s a = *(const v8s*)&qr[i0 + l15][k0 + quad * 8];
#pragma unroll
                for (int nt = 0; nt < 3; nt++) {
                    v8s bf = *(const v8s*)&band[xw + nt * 16 + l15][k0 + quad * 8];
                    racc[nt] = __builtin_amdgcn_mfma_f32_16x16x32_bf16(a, bf, racc[nt], 0, 0, 0);
                }
            }
#pragma unroll
            for (int nt = 0; nt < 3; nt++)
#pragma unroll
                for (int rg = 0; rg < 4; rg++)
                    Rw[w][quad * 4 + rg][nt * 16 + l15] = racc[nt][rg];
        }

        // ---- content GEMM: C[ii][j] = sum_d qc[i0+ii][d] * Kb[j][d] ----
        v4f cacc[2];
        cacc[0] = (v4f)(0.f); cacc[1] = (v4f)(0.f);
#pragma unroll
        for (int k0 = 0; k0 < 64; k0 += 32) {
            v8s a = *(const v8s*)&qc[i0 + l15][k0 + quad * 8];
#pragma unroll
            for (int nt = 0; nt < 2; nt++) {
                v8s bk = *(const v8s*)&Kb[nt * 16 + l15][k0 + quad * 8];
                cacc[nt] = __builtin_amdgcn_mfma_f32_16x16x32_bf16(a, bk, cacc[nt], 0, 0, 0);
            }
        }

        // ---- scores + online softmax (fp32, rows within 16-lane groups) ----
#pragma unroll
        for (int rg = 0; rg < 4; rg++) {
            const int ii = quad * 4 + rg;
            float sc0 = (cacc[0][rg] + Rw[w][ii][(l15) - ii + 15]) * 0.125f;
            float sc1 = (cacc[1][rg] + Rw[w][ii][(16 + l15) - ii + 15]) * 0.125f;
            float mx = fmaxf(sc0, sc1);
#pragma unroll
            for (int off = 1; off < 16; off <<= 1)
                mx = fmaxf(mx, __shfl_xor(mx, off));
            float mn = fmaxf(m_i[rg], mx);
            float al = __expf(m_i[rg] - mn);
            float p0 = __expf(sc0 - mn), p1 = __expf(sc1 - mn);
            float rs = p0 + p1;
#pragma unroll
            for (int off = 1; off < 16; off <<= 1)
                rs += __shfl_xor(rs, off);
            l_i[rg] = l_i[rg] * al + rs;
            m_i[rg] = mn;
#pragma unroll
            for (int nt = 0; nt < 4; nt++) o_acc[nt][rg] *= al;
            Pb[w][ii][l15]      = f2bf(p0);
            Pb[w][ii][16 + l15] = f2bf(p1);
        }

        // ---- PV GEMM: o[ii][d] += sum_j P[ii][j] * Vt[d][j] ----
        {
            v8s pa = *(const v8s*)&Pb[w][l15][quad * 8];
#pragma unroll
            for (int nt = 0; nt < 4; nt++) {
                v8s vf = *(const v8s*)&Vt[nt * 16 + l15][quad * 8];
                o_acc[nt] = __builtin_amdgcn_mfma_f32_16x16x32_bf16(pa, vf, o_acc[nt], 0, 0, 0);
            }
        }
    }

    // ---- epilogue ----
#pragma unroll
    for (int rg = 0; rg < 4; rg++) {
        const float inv = 1.f / l_i[rg];
        const int row = s0 + i0 + quad * 4 + rg;
        const size_t base = ((size_t)b * SEQ + row) * CH + h * HD;
#pragma unroll
        for (int nt = 0; nt < 4; nt++)
            out[base + nt * 16 + l15] = o_acc[nt][rg] * inv;
    }
}

// ---------------------------------------------------------------------------
extern "C" void kernel_launch(void* const* d_in, const int* in_sizes, int n_in,
                              void* d_out, int out_size, void* d_ws, size_t ws_size,
                              hipStream_t stream)
{
    const float* src  = (const float*)d_in[0];
    const float* Wq   = (const float*)d_in[1];
    const float* bq   = (const float*)d_in[2];
    const float* Wk   = (const float*)d_in[3];
    const float* bk   = (const float*)d_in[4];
    const float* Wv   = (const float*)d_in[5];
    const float* bv   = (const float*)d_in[6];
    const float* relk = (const float*)d_in[7];
    float* out = (float*)d_out;

    const size_t nQKV = (size_t)BATCH * SEQ * CH;      // 4 Mi elements
    short* qb   = (short*)d_ws;
    short* kb   = qb + nQKV;
    short* vb   = kb + nQKV;
    short* relb = vb + nQKV;                           // (2S-1)*HD bf16

    // rel cast: (2*2048-1)*64 / 4 = 65520 float4 groups
    cast_rel_kernel<<<256, 256, 0, stream>>>(relk, relb, 65520);

    dim3 gProj(1024 / 128, 4096 / 128, 3);
    proj_gemm_kernel<<<gProj, 256, 0, stream>>>(src, Wq, bq, Wk, bk, Wv, bv,
                                                qb, kb, vb);

    dim3 gAttn(SEQ / 64, BHN);                          // (32, 32)
    attn_mfma_kernel<<<gAttn, 256, 0, stream>>>(qb, kb, vb, relb, out);
}

// Round 3
// 388.062 us; speedup vs baseline: 5.7986x; 1.7607x over previous
//
#include <hip/hip_runtime.h>

#define BATCH 2
#define SEQ   2048
#define CH    1024
#define NH    16
#define HD    64
#define BHN   (BATCH*NH)   /* 32 */
#define SD    (SEQ*HD)     /* 131072 */

typedef short v8s __attribute__((ext_vector_type(8)));
typedef short v4s __attribute__((ext_vector_type(4)));
typedef float v4f __attribute__((ext_vector_type(4)));

__device__ __forceinline__ short f2bf(float f) {
    unsigned u = __float_as_uint(f);
    u += 0x7fff + ((u >> 16) & 1);   // RNE; finite inputs
    return (short)(u >> 16);
}

__device__ __forceinline__ void gl_lds16(const short* g, short* l) {
    __builtin_amdgcn_global_load_lds(
        (const __attribute__((address_space(1))) void*)g,
        (__attribute__((address_space(3))) void*)l, 16, 0, 0);
}

// ---------------------------------------------------------------------------
// Fused fp32 -> bf16 cast for src / Wq / Wk / Wv / rel_k_table.
// ---------------------------------------------------------------------------
__global__ __launch_bounds__(256) void cast_all_kernel(
    const float* __restrict__ src, const float* __restrict__ wq,
    const float* __restrict__ wk, const float* __restrict__ wv,
    const float* __restrict__ rel,
    short* __restrict__ xb, short* __restrict__ wqb,
    short* __restrict__ wkb, short* __restrict__ wvb,
    short* __restrict__ relb)
{
    const int z = blockIdx.z;
    const float* s; short* d; int n4;
    switch (z) {
        case 0: s = src; d = xb;   n4 = 1048576; break;  // 4Mi elems
        case 1: s = wq;  d = wqb;  n4 = 262144;  break;
        case 2: s = wk;  d = wkb;  n4 = 262144;  break;
        case 3: s = wv;  d = wvb;  n4 = 262144;  break;
        default: s = rel; d = relb; n4 = 65520;  break;  // 4095*64/4
    }
    for (int i = blockIdx.x * 256 + threadIdx.x; i < n4; i += gridDim.x * 256) {
        float4 v = ((const float4*)s)[i];
        v4s o; o.x = f2bf(v.x); o.y = f2bf(v.y); o.z = f2bf(v.z); o.w = f2bf(v.w);
        ((v4s*)d)[i] = o;
    }
}

// ---------------------------------------------------------------------------
// bf16 MFMA projection GEMM: out[m][n] = sum_k X[m][k]*W[n][k] + bias[n]
// M=4096, N=K=1024. 128x128 tile, BK=32, global_load_lds width 16.
// 4 waves; wave (wm,wn) owns a 64x64 quadrant as 4x4 16x16 MFMA tiles.
// MFMA 16x16x32 bf16: A/B[m|n=lane&15][k=(lane>>4)*8+j]; C/D col=lane&15,
// row=(lane>>4)*4+reg.
// ---------------------------------------------------------------------------
__global__ __launch_bounds__(256, 3) void proj_mfma_kernel(
    const short* __restrict__ Xb,
    const short* __restrict__ Wqb, const short* __restrict__ Wkb,
    const short* __restrict__ Wvb,
    const float* __restrict__ bq, const float* __restrict__ bk,
    const float* __restrict__ bv,
    short* __restrict__ qo, short* __restrict__ ko, short* __restrict__ vo)
{
    const int z = blockIdx.z;
    const short* W    = (z == 0) ? Wqb : (z == 1) ? Wkb : Wvb;
    const float* bias = (z == 0) ? bq  : (z == 1) ? bk  : bv;
    short*       out  = (z == 0) ? qo  : (z == 1) ? ko  : vo;

    const int m0 = blockIdx.y * 128;
    const int n0 = blockIdx.x * 128;
    const int tid  = threadIdx.x;
    const int w    = tid >> 6;
    const int lane = tid & 63;
    const int l15  = lane & 15;
    const int quad = lane >> 4;
    const int wm = w & 1, wn = w >> 1;

    __shared__ short Al[128 * 32];   // [row][k], stride 32 (no pad: glds)
    __shared__ short Bl[128 * 32];

    v4f acc[4][4];
#pragma unroll
    for (int i = 0; i < 4; i++)
#pragma unroll
        for (int j = 0; j < 4; j++) acc[i][j] = (v4f)(0.f);

    const int lr = lane >> 2;          // 0..15 row-within-slab
    const int lc = (lane & 3) * 8;     // k-offset

    for (int k0 = 0; k0 < 1024; k0 += 32) {
        __syncthreads();
#pragma unroll
        for (int l = 0; l < 2; l++) {
            const int slab = w * 32 + l * 16;
            gl_lds16(Xb + (size_t)(m0 + slab + lr) * 1024 + k0 + lc,
                     &Al[slab * 32]);
            gl_lds16(W + (size_t)(n0 + slab + lr) * 1024 + k0 + lc,
                     &Bl[slab * 32]);
        }
        __syncthreads();
        v8s af[4], bf[4];
#pragma unroll
        for (int mt = 0; mt < 4; mt++)
            af[mt] = *(const v8s*)&Al[(wm * 64 + mt * 16 + l15) * 32 + quad * 8];
#pragma unroll
        for (int nt = 0; nt < 4; nt++)
            bf[nt] = *(const v8s*)&Bl[(wn * 64 + nt * 16 + l15) * 32 + quad * 8];
#pragma unroll
        for (int mt = 0; mt < 4; mt++)
#pragma unroll
            for (int nt = 0; nt < 4; nt++)
                acc[mt][nt] = __builtin_amdgcn_mfma_f32_16x16x32_bf16(
                    af[mt], bf[nt], acc[mt][nt], 0, 0, 0);
    }

    float bv4[4];
#pragma unroll
    for (int nt = 0; nt < 4; nt++)
        bv4[nt] = bias[n0 + wn * 64 + nt * 16 + l15];
#pragma unroll
    for (int mt = 0; mt < 4; mt++)
#pragma unroll
        for (int rg = 0; rg < 4; rg++) {
            const int row = m0 + wm * 64 + mt * 16 + quad * 4 + rg;
#pragma unroll
            for (int nt = 0; nt < 4; nt++)
                out[(size_t)row * 1024 + n0 + wn * 64 + nt * 16 + l15] =
                    f2bf(acc[mt][nt][rg] + bv4[nt]);
        }
}

// ---------------------------------------------------------------------------
// MFMA flash attention with relative-position scores (bf16 inputs).
//   score[i][t] = ( q[i]·k[t] + qr[i]·rel[t-i+2047] ) / 8
// Block: 64 q-rows × one bh; 4 waves, wave w owns rows i0=w*16..+15.
// K-tile 32. Rel-pos skew GEMM R[ii][x]=qr·band, gather pos=R[ii][j-ii+15].
// q fragments hoisted to registers; band read directly from global (L2).
// ---------------------------------------------------------------------------
__global__ __launch_bounds__(256, 4) void attn_mfma_kernel(
    const short* __restrict__ qb, const short* __restrict__ kb,
    const short* __restrict__ vb, const short* __restrict__ relb,
    float* __restrict__ out)
{
    const int tid  = threadIdx.x;
    const int w    = tid >> 6;
    const int lane = tid & 63;
    const int l15  = lane & 15;
    const int quad = lane >> 4;
    const int bh = blockIdx.y, b = bh >> 4, h = bh & 15;
    const int s0 = blockIdx.x * 64;
    const int i0 = w * 16;

    __shared__ short Kb[32][72];      // key tile
    __shared__ short Vt[64][40];      // V transposed: Vt[d][t]
    __shared__ float Rw[4][16][52];   // per-wave skew GEMM result
    __shared__ short Pb[4][16][40];   // per-wave P (bf16), PV A-operand

    // ---- hoist loop-invariant q fragments (both views) into registers ----
    v8s qc_f[2], qr_f[2];
#pragma unroll
    for (int kh = 0; kh < 2; kh++) {
        qc_f[kh] = *(const v8s*)(qb + (size_t)bh * SD +
                                 (size_t)(s0 + i0 + l15) * HD + kh * 32 + quad * 8);
        qr_f[kh] = *(const v8s*)(qb + (size_t)(s0 + i0 + l15) * (BHN * HD) +
                                 bh * HD + kh * 32 + quad * 8);
    }
    // band global row base per nt-tile: row = brow[nt] + t0, in [0, 4095]
    int brow[3];
#pragma unroll
    for (int nt = 0; nt < 3; nt++)
        brow[nt] = 2032 - s0 - i0 + nt * 16 + l15;

    v4f o_acc[4];
#pragma unroll
    for (int nt = 0; nt < 4; nt++) o_acc[nt] = (v4f)(0.f);
    float m_i[4] = {-1e30f, -1e30f, -1e30f, -1e30f};
    float l_i[4] = {0.f, 0.f, 0.f, 0.f};

    for (int t0 = 0; t0 < SEQ; t0 += 32) {
        __syncthreads();
        // ---- stage K tile ----
        {
            int t = tid >> 3, c = (tid & 7) * 8;
            *(v8s*)&Kb[t][c] =
                *(const v8s*)(kb + (size_t)bh * SD + (size_t)(t0 + t) * HD + c);
        }
        // ---- stage V tile transposed ----
        {
            int t = tid & 31, c = (tid >> 5) * 8;
            v8s vv = *(const v8s*)(vb + (size_t)bh * SD + (size_t)(t0 + t) * HD + c);
#pragma unroll
            for (int e = 0; e < 8; e++) Vt[c + e][t] = vv[e];
        }
        __syncthreads();

        // ---- skew GEMM: R[ii][x] = sum_d qr[i0+ii][d] * rel[brow[x>>4]+t0][d]
        {
            v4f racc[3];
#pragma unroll
            for (int nt = 0; nt < 3; nt++) racc[nt] = (v4f)(0.f);
#pragma unroll
            for (int kh = 0; kh < 2; kh++) {
#pragma unroll
                for (int nt = 0; nt < 3; nt++) {
                    v8s bf = *(const v8s*)(relb + (size_t)(brow[nt] + t0) * HD +
                                           kh * 32 + quad * 8);
                    racc[nt] = __builtin_amdgcn_mfma_f32_16x16x32_bf16(
                        qr_f[kh], bf, racc[nt], 0, 0, 0);
                }
            }
#pragma unroll
            for (int nt = 0; nt < 3; nt++)
#pragma unroll
                for (int rg = 0; rg < 4; rg++)
                    Rw[w][quad * 4 + rg][nt * 16 + l15] = racc[nt][rg];
        }

        // ---- content GEMM ----
        v4f cacc[2];
        cacc[0] = (v4f)(0.f); cacc[1] = (v4f)(0.f);
#pragma unroll
        for (int kh = 0; kh < 2; kh++) {
#pragma unroll
            for (int nt = 0; nt < 2; nt++) {
                v8s bk = *(const v8s*)&Kb[nt * 16 + l15][kh * 32 + quad * 8];
                cacc[nt] = __builtin_amdgcn_mfma_f32_16x16x32_bf16(
                    qc_f[kh], bk, cacc[nt], 0, 0, 0);
            }
        }

        // ---- scores + online softmax ----
#pragma unroll
        for (int rg = 0; rg < 4; rg++) {
            const int ii = quad * 4 + rg;
            float sc0 = (cacc[0][rg] + Rw[w][ii][l15 - ii + 15]) * 0.125f;
            float sc1 = (cacc[1][rg] + Rw[w][ii][16 + l15 - ii + 15]) * 0.125f;
            float mx = fmaxf(sc0, sc1);
#pragma unroll
            for (int off = 1; off < 16; off <<= 1)
                mx = fmaxf(mx, __shfl_xor(mx, off));
            float mn = fmaxf(m_i[rg], mx);
            float al = __expf(m_i[rg] - mn);
            float p0 = __expf(sc0 - mn), p1 = __expf(sc1 - mn);
            float rs = p0 + p1;
#pragma unroll
            for (int off = 1; off < 16; off <<= 1)
                rs += __shfl_xor(rs, off);
            l_i[rg] = l_i[rg] * al + rs;
            m_i[rg] = mn;
#pragma unroll
            for (int nt = 0; nt < 4; nt++) o_acc[nt][rg] *= al;
            Pb[w][ii][l15]      = f2bf(p0);
            Pb[w][ii][16 + l15] = f2bf(p1);
        }

        // ---- PV GEMM ----
        {
            v8s pa = *(const v8s*)&Pb[w][l15][quad * 8];
#pragma unroll
            for (int nt = 0; nt < 4; nt++) {
                v8s vf = *(const v8s*)&Vt[nt * 16 + l15][quad * 8];
                o_acc[nt] = __builtin_amdgcn_mfma_f32_16x16x32_bf16(
                    pa, vf, o_acc[nt], 0, 0, 0);
            }
        }
    }

    // ---- epilogue ----
#pragma unroll
    for (int rg = 0; rg < 4; rg++) {
        const float inv = 1.f / l_i[rg];
        const int row = s0 + i0 + quad * 4 + rg;
        const size_t base = ((size_t)b * SEQ + row) * CH + h * HD;
#pragma unroll
        for (int nt = 0; nt < 4; nt++)
            out[base + nt * 16 + l15] = o_acc[nt][rg] * inv;
    }
}

// ---------------------------------------------------------------------------
extern "C" void kernel_launch(void* const* d_in, const int* in_sizes, int n_in,
                              void* d_out, int out_size, void* d_ws, size_t ws_size,
                              hipStream_t stream)
{
    const float* src  = (const float*)d_in[0];
    const float* Wq   = (const float*)d_in[1];
    const float* bq   = (const float*)d_in[2];
    const float* Wk   = (const float*)d_in[3];
    const float* bk   = (const float*)d_in[4];
    const float* Wv   = (const float*)d_in[5];
    const float* bv   = (const float*)d_in[6];
    const float* relk = (const float*)d_in[7];
    float* out = (float*)d_out;

    const size_t nQKV = (size_t)BATCH * SEQ * CH;      // 4 Mi elements
    const size_t nW   = (size_t)CH * CH;               // 1 Mi
    short* qb   = (short*)d_ws;
    short* kb   = qb + nQKV;
    short* vb   = kb + nQKV;
    short* xb   = vb + nQKV;
    short* wqb  = xb + nQKV;
    short* wkb  = wqb + nW;
    short* wvb  = wkb + nW;
    short* relb = wvb + nW;                            // 4095*64 bf16

    cast_all_kernel<<<dim3(512, 1, 5), 256, 0, stream>>>(
        src, Wq, Wk, Wv, relk, xb, wqb, wkb, wvb, relb);

    dim3 gProj(1024 / 128, 4096 / 128, 3);             // (8, 32, 3)
    proj_mfma_kernel<<<gProj, 256, 0, stream>>>(
        xb, wqb, wkb, wvb, bq, bk, bv, qb, kb, vb);

    dim3 gAttn(SEQ / 64, BHN);                          // (32, 32)
    attn_mfma_kernel<<<gAttn, 256, 0, stream>>>(qb, kb, vb, relb, out);
}

// Round 4
// 315.290 us; speedup vs baseline: 7.1369x; 1.2308x over previous
//
#include <hip/hip_runtime.h>

#define BATCH 2
#define SEQ   2048
#define CH    1024
#define NH    16
#define HD    64
#define BHN   (BATCH*NH)   /* 32 */
#define SD    (SEQ*HD)     /* 131072 */

typedef short v8s __attribute__((ext_vector_type(8)));
typedef short v4s __attribute__((ext_vector_type(4)));
typedef float v4f __attribute__((ext_vector_type(4)));

__device__ __forceinline__ short f2bf(float f) {
    unsigned u = __float_as_uint(f);
    u += 0x7fff + ((u >> 16) & 1);   // RNE; finite inputs
    return (short)(u >> 16);
}

__device__ __forceinline__ void gl_lds16(const short* g, short* l) {
    __builtin_amdgcn_global_load_lds(
        (const __attribute__((address_space(1))) void*)g,
        (__attribute__((address_space(3))) void*)l, 16, 0, 0);
}

// ---------------------------------------------------------------------------
// Fused fp32 -> bf16 cast for src / Wq / Wk / Wv / rel_k_table.
// ---------------------------------------------------------------------------
__global__ __launch_bounds__(256) void cast_all_kernel(
    const float* __restrict__ src, const float* __restrict__ wq,
    const float* __restrict__ wk, const float* __restrict__ wv,
    const float* __restrict__ rel,
    short* __restrict__ xb, short* __restrict__ wqb,
    short* __restrict__ wkb, short* __restrict__ wvb,
    short* __restrict__ relb)
{
    const int z = blockIdx.z;
    const float* s; short* d; int n4;
    switch (z) {
        case 0: s = src; d = xb;   n4 = 1048576; break;  // 4Mi elems
        case 1: s = wq;  d = wqb;  n4 = 262144;  break;
        case 2: s = wk;  d = wkb;  n4 = 262144;  break;
        case 3: s = wv;  d = wvb;  n4 = 262144;  break;
        default: s = rel; d = relb; n4 = 65520;  break;  // 4095*64/4
    }
    for (int i = blockIdx.x * 256 + threadIdx.x; i < n4; i += gridDim.x * 256) {
        float4 v = ((const float4*)s)[i];
        v4s o; o.x = f2bf(v.x); o.y = f2bf(v.y); o.z = f2bf(v.z); o.w = f2bf(v.w);
        ((v4s*)d)[i] = o;
    }
}

// ---------------------------------------------------------------------------
// bf16 MFMA projection GEMM: out[m][n] = sum_k X[m][k]*W[n][k] + bias[n]
// M=4096, N=K=1024. 128x128 tile, BK=32, global_load_lds width 16.
// ---------------------------------------------------------------------------
__global__ __launch_bounds__(256, 3) void proj_mfma_kernel(
    const short* __restrict__ Xb,
    const short* __restrict__ Wqb, const short* __restrict__ Wkb,
    const short* __restrict__ Wvb,
    const float* __restrict__ bq, const float* __restrict__ bk,
    const float* __restrict__ bv,
    short* __restrict__ qo, short* __restrict__ ko, short* __restrict__ vo)
{
    const int z = blockIdx.z;
    const short* W    = (z == 0) ? Wqb : (z == 1) ? Wkb : Wvb;
    const float* bias = (z == 0) ? bq  : (z == 1) ? bk  : bv;
    short*       out  = (z == 0) ? qo  : (z == 1) ? ko  : vo;

    const int m0 = blockIdx.y * 128;
    const int n0 = blockIdx.x * 128;
    const int tid  = threadIdx.x;
    const int w    = tid >> 6;
    const int lane = tid & 63;
    const int l15  = lane & 15;
    const int quad = lane >> 4;
    const int wm = w & 1, wn = w >> 1;

    __shared__ short Al[128 * 32];   // [row][k], stride 32 (no pad: glds)
    __shared__ short Bl[128 * 32];

    v4f acc[4][4];
#pragma unroll
    for (int i = 0; i < 4; i++)
#pragma unroll
        for (int j = 0; j < 4; j++) acc[i][j] = (v4f)(0.f);

    const int lr = lane >> 2;          // 0..15 row-within-slab
    const int lc = (lane & 3) * 8;     // k-offset

    for (int k0 = 0; k0 < 1024; k0 += 32) {
        __syncthreads();
#pragma unroll
        for (int l = 0; l < 2; l++) {
            const int slab = w * 32 + l * 16;
            gl_lds16(Xb + (size_t)(m0 + slab + lr) * 1024 + k0 + lc,
                     &Al[slab * 32]);
            gl_lds16(W + (size_t)(n0 + slab + lr) * 1024 + k0 + lc,
                     &Bl[slab * 32]);
        }
        __syncthreads();
        v8s af[4], bf[4];
#pragma unroll
        for (int mt = 0; mt < 4; mt++)
            af[mt] = *(const v8s*)&Al[(wm * 64 + mt * 16 + l15) * 32 + quad * 8];
#pragma unroll
        for (int nt = 0; nt < 4; nt++)
            bf[nt] = *(const v8s*)&Bl[(wn * 64 + nt * 16 + l15) * 32 + quad * 8];
#pragma unroll
        for (int mt = 0; mt < 4; mt++)
#pragma unroll
            for (int nt = 0; nt < 4; nt++)
                acc[mt][nt] = __builtin_amdgcn_mfma_f32_16x16x32_bf16(
                    af[mt], bf[nt], acc[mt][nt], 0, 0, 0);
    }

    float bv4[4];
#pragma unroll
    for (int nt = 0; nt < 4; nt++)
        bv4[nt] = bias[n0 + wn * 64 + nt * 16 + l15];
#pragma unroll
    for (int mt = 0; mt < 4; mt++)
#pragma unroll
        for (int rg = 0; rg < 4; rg++) {
            const int row = m0 + wm * 64 + mt * 16 + quad * 4 + rg;
#pragma unroll
            for (int nt = 0; nt < 4; nt++)
                out[(size_t)row * 1024 + n0 + wn * 64 + nt * 16 + l15] =
                    f2bf(acc[mt][nt][rg] + bv4[nt]);
        }
}

// ---------------------------------------------------------------------------
// MFMA flash attention with relative-position scores (bf16 inputs).
//   score[i][t] = ( q[i]·k[t] + qr[i]·rel[t-i+2047] ) / 8
// Block: 64 q-rows × one bh; 4 waves, wave w owns rows i0=w*16..+15.
// K-tile 64 (32 iterations). Rel-pos skew GEMM over the wave's 80-wide
// diagonal window; gather pos = R[ii][j-ii+15] via intra-quad shfl of the
// C-layout registers (no LDS round-trip):
//   x = jt*16 + e, e = l15+15-ii in [0,30]
//   -> src lane quad*16+(e&15), register racc[jt+(e>=16)][rg].
// ---------------------------------------------------------------------------
__global__ __launch_bounds__(256, 4) void attn_mfma_kernel(
    const short* __restrict__ qb, const short* __restrict__ kb,
    const short* __restrict__ vb, const short* __restrict__ relb,
    float* __restrict__ out)
{
    const int tid  = threadIdx.x;
    const int w    = tid >> 6;
    const int lane = tid & 63;
    const int l15  = lane & 15;
    const int quad = lane >> 4;
    const int bh = blockIdx.y, b = bh >> 4, h = bh & 15;
    const int s0 = blockIdx.x * 64;
    const int i0 = w * 16;

    __shared__ short Kb[64][72];      // key tile
    __shared__ short Vt[64][72];      // V transposed: Vt[d][t]
    __shared__ short Pb[4][16][72];   // per-wave P (bf16), PV A-operand

    // ---- hoist loop-invariant q fragments (both views) into registers ----
    v8s qc_f[2], qr_f[2];
#pragma unroll
    for (int kh = 0; kh < 2; kh++) {
        qc_f[kh] = *(const v8s*)(qb + (size_t)bh * SD +
                                 (size_t)(s0 + i0 + l15) * HD + kh * 32 + quad * 8);
        qr_f[kh] = *(const v8s*)(qb + (size_t)(s0 + i0 + l15) * (BHN * HD) +
                                 bh * HD + kh * 32 + quad * 8);
    }
    // band global row base per nt-tile: row = brow[nt] + t0, x = nt*16+l15
    int brow[5];
#pragma unroll
    for (int nt = 0; nt < 5; nt++)
        brow[nt] = 2032 - s0 - i0 + nt * 16 + l15;

    v4f o_acc[4];
#pragma unroll
    for (int nt = 0; nt < 4; nt++) o_acc[nt] = (v4f)(0.f);
    float m_i[4] = {-1e30f, -1e30f, -1e30f, -1e30f};
    float l_i[4] = {0.f, 0.f, 0.f, 0.f};

    const int tK = tid >> 2, cK = (tid & 3) * 16;          // K staging
    const int tV = tid & 63, cV = (tid >> 6) * 16;         // V staging

    for (int t0 = 0; t0 < SEQ; t0 += 64) {
        __syncthreads();
        // ---- stage K tile (64x64) ----
        {
            const short* kp = kb + (size_t)bh * SD + (size_t)(t0 + tK) * HD + cK;
            *(v8s*)&Kb[tK][cK]     = *(const v8s*)kp;
            *(v8s*)&Kb[tK][cK + 8] = *(const v8s*)(kp + 8);
        }
        // ---- stage V tile transposed ----
        {
            const short* vp = vb + (size_t)bh * SD + (size_t)(t0 + tV) * HD + cV;
            v8s v0 = *(const v8s*)vp;
            v8s v1 = *(const v8s*)(vp + 8);
#pragma unroll
            for (int e = 0; e < 8; e++) {
                Vt[cV + e][tV]     = v0[e];
                Vt[cV + 8 + e][tV] = v1[e];
            }
        }
        __syncthreads();

        // ---- skew GEMM: R[ii][x] = sum_d qr[i0+ii][d] * rel[u0+x][d] ----
        v4f racc[5];
#pragma unroll
        for (int nt = 0; nt < 5; nt++) racc[nt] = (v4f)(0.f);
#pragma unroll
        for (int kh = 0; kh < 2; kh++) {
#pragma unroll
            for (int nt = 0; nt < 5; nt++) {
                int row = brow[nt] + t0;
                if (nt == 4) row = min(row, 4094);   // x=79 unused; clamp OOB
                v8s bf = *(const v8s*)(relb + (size_t)row * HD + kh * 32 + quad * 8);
                racc[nt] = __builtin_amdgcn_mfma_f32_16x16x32_bf16(
                    qr_f[kh], bf, racc[nt], 0, 0, 0);
            }
        }

        // ---- content GEMM: C[ii][j] = sum_d qc[i0+ii][d] * Kb[j][d] ----
        v4f cacc[4];
#pragma unroll
        for (int nt = 0; nt < 4; nt++) cacc[nt] = (v4f)(0.f);
#pragma unroll
        for (int kh = 0; kh < 2; kh++) {
#pragma unroll
            for (int nt = 0; nt < 4; nt++) {
                v8s bk = *(const v8s*)&Kb[nt * 16 + l15][kh * 32 + quad * 8];
                cacc[nt] = __builtin_amdgcn_mfma_f32_16x16x32_bf16(
                    qc_f[kh], bk, cacc[nt], 0, 0, 0);
            }
        }

        // ---- scores + online softmax (shfl-gathered rel term) ----
#pragma unroll
        for (int rg = 0; rg < 4; rg++) {
            const int ii = quad * 4 + rg;
            const int e  = l15 + 15 - ii;          // [0,30]
            const int sl = quad * 16 + (e & 15);
            float sc[4];
#pragma unroll
            for (int jt = 0; jt < 4; jt++) {
                float va = __shfl(racc[jt][rg], sl);
                float vb2 = __shfl(racc[jt + 1][rg], sl);
                float pos = (e < 16) ? va : vb2;
                sc[jt] = (cacc[jt][rg] + pos) * 0.125f;
            }
            float mx = fmaxf(fmaxf(sc[0], sc[1]), fmaxf(sc[2], sc[3]));
#pragma unroll
            for (int off = 1; off < 16; off <<= 1)
                mx = fmaxf(mx, __shfl_xor(mx, off));
            float mn = fmaxf(m_i[rg], mx);
            float al = __expf(m_i[rg] - mn);
            float p[4], rs = 0.f;
#pragma unroll
            for (int jt = 0; jt < 4; jt++) { p[jt] = __expf(sc[jt] - mn); rs += p[jt]; }
#pragma unroll
            for (int off = 1; off < 16; off <<= 1)
                rs += __shfl_xor(rs, off);
            l_i[rg] = l_i[rg] * al + rs;
            m_i[rg] = mn;
#pragma unroll
            for (int nt = 0; nt < 4; nt++) o_acc[nt][rg] *= al;
#pragma unroll
            for (int jt = 0; jt < 4; jt++)
                Pb[w][ii][jt * 16 + l15] = f2bf(p[jt]);
        }

        // ---- PV GEMM: o[ii][d] += sum_j P[ii][j] * Vt[d][j] ----
#pragma unroll
        for (int kh = 0; kh < 2; kh++) {
            v8s pa = *(const v8s*)&Pb[w][l15][kh * 32 + quad * 8];
#pragma unroll
            for (int nt = 0; nt < 4; nt++) {
                v8s vf = *(const v8s*)&Vt[nt * 16 + l15][kh * 32 + quad * 8];
                o_acc[nt] = __builtin_amdgcn_mfma_f32_16x16x32_bf16(
                    pa, vf, o_acc[nt], 0, 0, 0);
            }
        }
    }

    // ---- epilogue ----
#pragma unroll
    for (int rg = 0; rg < 4; rg++) {
        const float inv = 1.f / l_i[rg];
        const int row = s0 + i0 + quad * 4 + rg;
        const size_t base = ((size_t)b * SEQ + row) * CH + h * HD;
#pragma unroll
        for (int nt = 0; nt < 4; nt++)
            out[base + nt * 16 + l15] = o_acc[nt][rg] * inv;
    }
}

// ---------------------------------------------------------------------------
extern "C" void kernel_launch(void* const* d_in, const int* in_sizes, int n_in,
                              void* d_out, int out_size, void* d_ws, size_t ws_size,
                              hipStream_t stream)
{
    const float* src  = (const float*)d_in[0];
    const float* Wq   = (const float*)d_in[1];
    const float* bq   = (const float*)d_in[2];
    const float* Wk   = (const float*)d_in[3];
    const float* bk   = (const float*)d_in[4];
    const float* Wv   = (const float*)d_in[5];
    const float* bv   = (const float*)d_in[6];
    const float* relk = (const float*)d_in[7];
    float* out = (float*)d_out;

    const size_t nQKV = (size_t)BATCH * SEQ * CH;      // 4 Mi elements
    const size_t nW   = (size_t)CH * CH;               // 1 Mi
    short* qb   = (short*)d_ws;
    short* kb   = qb + nQKV;
    short* vb   = kb + nQKV;
    short* xb   = vb + nQKV;
    short* wqb  = xb + nQKV;
    short* wkb  = wqb + nW;
    short* wvb  = wkb + nW;
    short* relb = wvb + nW;                            // 4095*64 bf16

    cast_all_kernel<<<dim3(512, 1, 5), 256, 0, stream>>>(
        src, Wq, Wk, Wv, relk, xb, wqb, wkb, wvb, relb);

    dim3 gProj(1024 / 128, 4096 / 128, 3);             // (8, 32, 3)
    proj_mfma_kernel<<<gProj, 256, 0, stream>>>(
        xb, wqb, wkb, wvb, bq, bk, bv, qb, kb, vb);

    dim3 gAttn(SEQ / 64, BHN);                          // (32, 32)
    attn_mfma_kernel<<<gAttn, 256, 0, stream>>>(qb, kb, vb, relb, out);
}